// Round 12
// baseline (96.136 us; speedup 1.0000x reference)
//
#include <hip/hip_runtime.h>
#include <hip/hip_bf16.h>

// Problem constants
#define S_TOT 37448      // input tokens per sample
#define OUT_ROWS 5704    // output rows per sample
#define EDIM 256
#define BATCH 8

typedef __attribute__((ext_vector_type(8))) short short8;
typedef __attribute__((ext_vector_type(4))) float f32x4;
typedef __attribute__((ext_vector_type(4))) unsigned int u32x4;

__device__ __forceinline__ short f2b(float f) {   // f32 -> bf16 RNE
    unsigned u = __builtin_bit_cast(unsigned, f);
    unsigned r = (u + 0x7fffu + ((u >> 16) & 1u)) >> 16;
    return (short)r;
}
__device__ __forceinline__ float b2f(short s) {
    unsigned u = ((unsigned)(unsigned short)s) << 16;
    return __builtin_bit_cast(float, u);
}

__device__ __forceinline__ void embed8f(const float* ve, const float* de,
                                        const float* q0, const float* q1, const float* q2,
                                        float* s) {
#pragma unroll
    for (int h = 0; h < 2; ++h) {
        f32x4 a = *(const f32x4*)(ve + h * 4);
        f32x4 b = *(const f32x4*)(de + h * 4);
        f32x4 c = *(const f32x4*)(q0 + h * 4);
        f32x4 d = *(const f32x4*)(q1 + h * 4);
        f32x4 e = *(const f32x4*)(q2 + h * 4);
#pragma unroll
        for (int j = 0; j < 4; ++j)
            s[h * 4 + j] = a[j] + b[j] + c[j] + d[j] + e[j];
    }
}

// unpack short8 (8 bf16) and add into a[0..7]
__device__ __forceinline__ void acc_bf8(float* a, short8 s) {
    u32x4 u = __builtin_bit_cast(u32x4, s);
#pragma unroll
    for (int j = 0; j < 4; ++j) {
        a[2 * j]     += __builtin_bit_cast(float, u[j] << 16);
        a[2 * j + 1] += __builtin_bit_cast(float, u[j] & 0xffff0000u);
    }
}

// -------- fused precompute (transform folded in): P[k][R][o] (bf16) --------
// P[k][R][o] = sum_i T[R][i] * bf16(w[o,i,k]),  rows R: [0,17)=val+dep,
// [17,81)=pos0, [81,145)=pos1, [145,209)=pos2, [209,256)=zero.
// bid = k*4 + mt. B-fragment read directly from w (no wt2 staging):
// o = nfg*16+(lane&15), i = ks*32+((lane>>4)<<3)+j, kpos = k.
template <int S>
__device__ __forceinline__ void precompute_body(
        const float* __restrict__ val_emb, const float* __restrict__ dep_emb,
        const float* __restrict__ pos_emb, const float* __restrict__ w,
        short* __restrict__ P, int bid, int tid, short* As) {
    constexpr int LI = (S == 4) ? 3 : 4;
    const int lane = tid & 63;
    const int wid = tid >> 6;
    const int wave_m = wid >> 1;
    const int wave_n = wid & 1;
    const int k  = bid >> 2;
    const int mt = bid & 3;

    f32x4 acc[2][8];
#pragma unroll
    for (int i = 0; i < 2; ++i)
#pragma unroll
        for (int j = 0; j < 8; ++j) acc[i][j] = (f32x4){0.f, 0.f, 0.f, 0.f};

    const int tk = tid >> 5;
    const int f0 = (tid & 31) * 8;
    const float* dep = dep_emb + (LI * 33 + LI + 1) * 256;   // depth row for this layer

#pragma unroll
    for (int m8 = 0; m8 < 8; ++m8) {
        int m = m8 * 8 + tk;
        int R = mt * 64 + m;
        short8 r;
        if (R < 17) {
            const float* src = val_emb + (LI * 17 + R) * 256;
#pragma unroll
            for (int j = 0; j < 8; ++j) r[j] = f2b(src[f0 + j] + dep[f0 + j]);
        } else if (R < 209) {
            int ax = (R < 81) ? 0 : (R < 145 ? 1 : 2);
            int rr = R - (ax == 0 ? 17 : (ax == 1 ? 81 : 145));
            const float* src = pos_emb + ((LI * 3 + ax) * 64 + rr) * 256;
#pragma unroll
            for (int j = 0; j < 8; ++j) r[j] = f2b(src[f0 + j]);
        } else {
            r = (short8){0, 0, 0, 0, 0, 0, 0, 0};
        }
        int byte = (m * 512 + f0 * 2) ^ ((m & 7) << 4);
        *(short8*)((char*)As + byte) = r;
    }
    __syncthreads();

#pragma unroll
    for (int ks = 0; ks < 8; ++ks) {
        short8 af[2];
#pragma unroll
        for (int mf = 0; mf < 2; ++mf) {
            int m = wave_m * 32 + mf * 16 + (lane & 15);
            int byte = (m * 512 + ks * 64 + ((lane >> 4) << 4)) ^ ((m & 7) << 4);
            af[mf] = *(const short8*)((const char*)As + byte);
        }
        const int ib = ks * 32 + ((lane >> 4) << 3);
#pragma unroll
        for (int nf = 0; nf < 8; ++nf) {
            int nfg = wave_n * 8 + nf;
            const float* wb = w + ((long)((nfg * 16 + (lane & 15)) * 256 + ib)) * S + k;
            short8 bfr;
#pragma unroll
            for (int j = 0; j < 8; ++j) bfr[j] = f2b(wb[j * S]);
            acc[0][nf] = __builtin_amdgcn_mfma_f32_16x16x32_bf16(af[0], bfr, acc[0][nf], 0, 0, 0);
            acc[1][nf] = __builtin_amdgcn_mfma_f32_16x16x32_bf16(af[1], bfr, acc[1][nf], 0, 0, 0);
        }
    }

#pragma unroll
    for (int mf = 0; mf < 2; ++mf) {
#pragma unroll
        for (int nf = 0; nf < 8; ++nf) {
            int n = wave_n * 128 + nf * 16 + (lane & 15);
            int r0 = mt * 64 + wave_m * 32 + mf * 16 + ((lane >> 4) << 2);
#pragma unroll
            for (int reg = 0; reg < 4; ++reg)
                P[(k * 256 + r0 + reg) * 256 + n] = f2b(acc[mf][nf][reg]);
        }
    }
}

__global__ __launch_bounds__(256) void precompute_fused(
        const float* __restrict__ val_emb, const float* __restrict__ dep_emb,
        const float* __restrict__ pos_emb, const float* __restrict__ w4,
        const float* __restrict__ w8, short* __restrict__ P4, short* __restrict__ P8) {
    __shared__ __align__(16) short As[64 * 256];
    if (blockIdx.x < 16)
        precompute_body<4>(val_emb, dep_emb, pos_emb, w4, P4, blockIdx.x, threadIdx.x, As);
    else
        precompute_body<8>(val_emb, dep_emb, pos_emb, w8, P8, blockIdx.x - 16, threadIdx.x, As);
}

// -------- gather-sum of bf16 projected rows (1-ahead software pipeline) --------
template <int S>
__device__ __forceinline__ void gather_body(
        const int* __restrict__ value, const int* __restrict__ position,
        const short* __restrict__ P, const float* __restrict__ bias,
        float* __restrict__ out, int bid, int tid, int4* idx_lds) {
    constexpr int L_OUT = (S == 4) ? 1024 : 4096;
    constexpr int OFF_IN = (S == 4) ? 584 : 4680;
    constexpr int OFF_OUT = (S == 4) ? 584 : 1608;

    const int R0 = bid * 8;
    if (tid < 8 * S) {
        int r = tid / S, k = tid - r * S;
        int R = R0 + r;
        int b = R / L_OUT, l = R - b * L_OUT;
        int t = b * S_TOT + OFF_IN + l * S + k;
        int v = value[t];
        const int* pp = position + t * 3;
        idx_lds[r * S + k] = make_int4(v << 8, (17 + pp[0]) << 8,
                                       (81 + pp[1]) << 8, (145 + pp[2]) << 8);
    }
    __syncthreads();

    const int r = tid >> 5;
    const int og = (tid & 31) * 8;
    const int R = R0 + r;
    const int b = R / L_OUT, l = R - b * L_OUT;

    float a[8];
    f32x4 b0 = *(const f32x4*)(bias + og);
    f32x4 b1 = *(const f32x4*)(bias + og + 4);
#pragma unroll
    for (int j = 0; j < 4; ++j) { a[j] = b0[j]; a[4 + j] = b1[j]; }

    const short* Pg = P + og;
    int4 id0 = idx_lds[r * S];
    short8 s0 = *(const short8*)(Pg + id0.x);
    short8 s1 = *(const short8*)(Pg + id0.y);
    short8 s2 = *(const short8*)(Pg + id0.z);
    short8 s3 = *(const short8*)(Pg + id0.w);
#pragma unroll
    for (int k = 0; k < S; ++k) {
        short8 t0 = s0, t1 = s1, t2 = s2, t3 = s3;
        if (k + 1 < S) {
            int4 idn = idx_lds[r * S + k + 1];
            const short* Pn = Pg + ((k + 1) << 16);
            t0 = *(const short8*)(Pn + idn.x);
            t1 = *(const short8*)(Pn + idn.y);
            t2 = *(const short8*)(Pn + idn.z);
            t3 = *(const short8*)(Pn + idn.w);
        }
        acc_bf8(a, s0);
        acc_bf8(a, s1);
        acc_bf8(a, s2);
        acc_bf8(a, s3);
        s0 = t0; s1 = t1; s2 = t2; s3 = t3;
    }

    float* op = out + ((long)b * OUT_ROWS + OFF_OUT + l) * EDIM + og;
    *(f32x4*)op = (f32x4){a[0], a[1], a[2], a[3]};
    *(f32x4*)(op + 4) = (f32x4){a[4], a[5], a[6], a[7]};
}

// -------- layers 0..2: pure embedding, f32 out --------
__device__ __forceinline__ void embed_small_body(
        const int* __restrict__ value, const int* __restrict__ depth,
        const int* __restrict__ position, const float* __restrict__ val_emb,
        const float* __restrict__ dep_emb, const float* __restrict__ pos_emb,
        float* __restrict__ out, int bid, int tid) {
    int idx = bid * 256 + tid;
    int token = idx >> 5;
    int f0 = (idx & 31) * 8;
    int b = token / 584;
    int r = token - b * 584;
    int li = (r < 8) ? 0 : (r < 72 ? 1 : 2);
    int base = b * S_TOT + r;
    int v = value[base];
    int d = depth[base];
    const int* pp = position + base * 3;
    const float* ve = val_emb + ((li * 17 + v) << 8) + f0;
    const float* de = dep_emb + ((li * 33 + d) << 8) + f0;
    const float* q0 = pos_emb + (((li * 3 + 0) * 64 + pp[0]) << 8) + f0;
    const float* q1 = pos_emb + (((li * 3 + 1) * 64 + pp[1]) << 8) + f0;
    const float* q2 = pos_emb + (((li * 3 + 2) * 64 + pp[2]) << 8) + f0;
    float s[8];
    embed8f(ve, de, q0, q1, q2, s);
    float* op = out + ((long)b * OUT_ROWS + r) * EDIM + f0;
    *(f32x4*)op = (f32x4){s[0], s[1], s[2], s[3]};
    *(f32x4*)(op + 4) = (f32x4){s[4], s[5], s[6], s[7]};
}

// -------- mega kernel: gather8 | gather4 | small-embed, one launch --------
__global__ __launch_bounds__(256) void gather_mega(
        const int* __restrict__ value, const int* __restrict__ depth,
        const int* __restrict__ position, const float* __restrict__ val_emb,
        const float* __restrict__ dep_emb, const float* __restrict__ pos_emb,
        const short* __restrict__ P4, const short* __restrict__ P8,
        const float* __restrict__ b4, const float* __restrict__ b8,
        float* __restrict__ out) {
    __shared__ int4 idx_lds[64];
    int bid = blockIdx.x, tid = threadIdx.x;
    if (bid < 4096)
        gather_body<8>(value, position, P8, b8, out, bid, tid, idx_lds);
    else if (bid < 5120)
        gather_body<4>(value, position, P4, b4, out, bid - 4096, tid, idx_lds);
    else
        embed_small_body(value, depth, position, val_emb, dep_emb, pos_emb, out, bid - 5120, tid);
}

// ================= FALLBACK path (round-8 validated) =================
template <int S>
__device__ __forceinline__ void transform_body(const float* __restrict__ w,
                                               short* __restrict__ dst, int bid, int tid) {
    int idx = bid * 256 + tid;
    int l  = idx & 63;
    int nf = (idx >> 6) & 15;
    int kb = idx >> 10;
    int o = nf * 16 + (l & 15);
    int kap0 = kb * 32 + ((l >> 4) << 3);
    short8 r;
#pragma unroll
    for (int j = 0; j < 8; ++j) {
        int kap = kap0 + j;
        int kpos = kap >> 8;
        int i = kap & 255;
        r[j] = f2b(w[(o * 256 + i) * S + kpos]);
    }
    *(short8*)(dst + idx * 8) = r;
}

__global__ __launch_bounds__(256) void transform_both(
        const float* __restrict__ w4, const float* __restrict__ w8,
        short* __restrict__ wt4, short* __restrict__ wt8) {
    int bid = blockIdx.x, tid = threadIdx.x;
    if (bid < 128) transform_body<4>(w4, wt4, bid, tid);
    else           transform_body<8>(w8, wt8, bid - 128, tid);
}

__global__ __launch_bounds__(256) void embed_small_kernel(
        const int* __restrict__ value, const int* __restrict__ depth,
        const int* __restrict__ position, const float* __restrict__ val_emb,
        const float* __restrict__ dep_emb, const float* __restrict__ pos_emb,
        float* __restrict__ out) {
    embed_small_body(value, depth, position, val_emb, dep_emb, pos_emb, out,
                     blockIdx.x, threadIdx.x);
}

template <int S>
__global__ __launch_bounds__(256) void conv_kernel(
        const int* __restrict__ value, const int* __restrict__ depth,
        const int* __restrict__ position, const float* __restrict__ val_emb,
        const float* __restrict__ dep_emb, const float* __restrict__ pos_emb,
        const short* __restrict__ wt2, const float* __restrict__ bias,
        float* __restrict__ out) {
    constexpr int LI = (S == 4) ? 3 : 4;
    constexpr int L_OUT = (S == 4) ? 1024 : 4096;
    constexpr int OFF_IN = (S == 4) ? 584 : 4680;
    constexpr int OFF_OUT = (S == 4) ? 584 : 1608;

    __shared__ __align__(16) short As[64 * 256];

    const int tid = threadIdx.x;
    const int lane = tid & 63;
    const int wid = tid >> 6;
    const int wave_m = wid >> 1;
    const int wave_n = wid & 1;
    const int mg0 = blockIdx.x * 64;
    const int b = mg0 / L_OUT;
    const int l0 = mg0 - b * L_OUT;

    f32x4 acc[2][8];
#pragma unroll
    for (int i = 0; i < 2; ++i)
#pragma unroll
        for (int j = 0; j < 8; ++j) acc[i][j] = (f32x4){0.f, 0.f, 0.f, 0.f};

    const int tk = tid >> 5;
    const int f0 = (tid & 31) * 8;

    for (int cp = 0; cp < S; ++cp) {
        __syncthreads();
#pragma unroll
        for (int m8 = 0; m8 < 8; ++m8) {
            int m = m8 * 8 + tk;
            int t = OFF_IN + (l0 + m) * S + cp;
            int base = b * S_TOT + t;
            int v = value[base];
            int d = depth[base];
            const int* pp = position + base * 3;
            const float* ve = val_emb + ((LI * 17 + v) << 8) + f0;
            const float* de = dep_emb + ((LI * 33 + d) << 8) + f0;
            const float* q0 = pos_emb + (((LI * 3 + 0) * 64 + pp[0]) << 8) + f0;
            const float* q1 = pos_emb + (((LI * 3 + 1) * 64 + pp[1]) << 8) + f0;
            const float* q2 = pos_emb + (((LI * 3 + 2) * 64 + pp[2]) << 8) + f0;
            float s[8];
            embed8f(ve, de, q0, q1, q2, s);
            short8 r;
#pragma unroll
            for (int j = 0; j < 8; ++j) r[j] = f2b(s[j]);
            int byte = (m * 512 + f0 * 2) ^ ((m & 7) << 4);
            *(short8*)((char*)As + byte) = r;
        }
        __syncthreads();
#pragma unroll
        for (int ks = 0; ks < 8; ++ks) {
            short8 af[2];
#pragma unroll
            for (int mf = 0; mf < 2; ++mf) {
                int m = wave_m * 32 + mf * 16 + (lane & 15);
                int byte = (m * 512 + ks * 64 + ((lane >> 4) << 4)) ^ ((m & 7) << 4);
                af[mf] = *(const short8*)((const char*)As + byte);
            }
            int kbg = cp * 8 + ks;
#pragma unroll
            for (int nf = 0; nf < 8; ++nf) {
                int nfg = wave_n * 8 + nf;
                short8 bfr = *(const short8*)(wt2 + ((kbg * 16 + nfg) * 64 + lane) * 8);
                acc[0][nf] = __builtin_amdgcn_mfma_f32_16x16x32_bf16(af[0], bfr, acc[0][nf], 0, 0, 0);
                acc[1][nf] = __builtin_amdgcn_mfma_f32_16x16x32_bf16(af[1], bfr, acc[1][nf], 0, 0, 0);
            }
        }
    }

#pragma unroll
    for (int mf = 0; mf < 2; ++mf) {
#pragma unroll
        for (int nf = 0; nf < 8; ++nf) {
            int n = wave_n * 128 + nf * 16 + (lane & 15);
            float bv = bias[n];
            int r0 = l0 + wave_m * 32 + mf * 16 + ((lane >> 4) << 2);
#pragma unroll
            for (int reg = 0; reg < 4; ++reg)
                out[((long)b * OUT_ROWS + OFF_OUT + r0 + reg) * EDIM + n] =
                    acc[mf][nf][reg] + bv;
        }
    }
}

extern "C" void kernel_launch(void* const* d_in, const int* in_sizes, int n_in,
                              void* d_out, int out_size, void* d_ws, size_t ws_size,
                              hipStream_t stream) {
    const int* value = (const int*)d_in[0];
    const int* depth = (const int*)d_in[1];
    const int* position = (const int*)d_in[2];
    const float* val_emb = (const float*)d_in[3];
    const float* dep_emb = (const float*)d_in[4];
    const float* pos_emb = (const float*)d_in[5];
    const float* w4 = (const float*)d_in[6];
    const float* b4 = (const float*)d_in[7];
    const float* w8 = (const float*)d_in[8];
    const float* b8 = (const float*)d_in[9];
    float* out = (float*)d_out;

    const size_t need = 1572864;                 // P4 (512 KB) + P8 (1 MB)

    if (ws_size >= need) {
        short* P4 = (short*)d_ws;                // 4*256*256 bf16
        short* P8 = P4 + 262144;                 // 8*256*256 bf16
        precompute_fused<<<dim3(48), dim3(256), 0, stream>>>(val_emb, dep_emb, pos_emb,
                                                             w4, w8, P4, P8);
        gather_mega<<<dim3(5704), dim3(256), 0, stream>>>(value, depth, position,
                                                          val_emb, dep_emb, pos_emb,
                                                          P4, P8, b4, b8, out);
    } else {
        short* wt4 = (short*)d_ws;               // 512 KB
        short* wt8 = wt4 + 262144;               // 1 MB
        transform_both<<<dim3(384), dim3(256), 0, stream>>>(w4, w8, wt4, wt8);
        embed_small_kernel<<<dim3(584), dim3(256), 0, stream>>>(value, depth, position,
                                                                val_emb, dep_emb, pos_emb, out);
        conv_kernel<4><<<dim3(128), dim3(256), 0, stream>>>(value, depth, position, val_emb,
                                                            dep_emb, pos_emb, wt4, b4, out);
        conv_kernel<8><<<dim3(512), dim3(256), 0, stream>>>(value, depth, position, val_emb,
                                                            dep_emb, pos_emb, wt8, b8, out);
    }
}

// Round 13
// 64.493 us; speedup vs baseline: 1.4906x; 1.4906x over previous
//
#include <hip/hip_runtime.h>
#include <hip/hip_bf16.h>

// Problem constants
#define S_TOT 37448      // input tokens per sample
#define OUT_ROWS 5704    // output rows per sample
#define EDIM 256
#define BATCH 8

typedef __attribute__((ext_vector_type(8))) short short8;
typedef __attribute__((ext_vector_type(4))) float f32x4;
typedef __attribute__((ext_vector_type(4))) unsigned int u32x4;

__device__ __forceinline__ short f2b(float f) {   // f32 -> bf16 RNE
    unsigned u = __builtin_bit_cast(unsigned, f);
    unsigned r = (u + 0x7fffu + ((u >> 16) & 1u)) >> 16;
    return (short)r;
}
__device__ __forceinline__ float b2f(short s) {
    unsigned u = ((unsigned)(unsigned short)s) << 16;
    return __builtin_bit_cast(float, u);
}

__device__ __forceinline__ void embed8f(const float* ve, const float* de,
                                        const float* q0, const float* q1, const float* q2,
                                        float* s) {
#pragma unroll
    for (int h = 0; h < 2; ++h) {
        f32x4 a = *(const f32x4*)(ve + h * 4);
        f32x4 b = *(const f32x4*)(de + h * 4);
        f32x4 c = *(const f32x4*)(q0 + h * 4);
        f32x4 d = *(const f32x4*)(q1 + h * 4);
        f32x4 e = *(const f32x4*)(q2 + h * 4);
#pragma unroll
        for (int j = 0; j < 4; ++j)
            s[h * 4 + j] = a[j] + b[j] + c[j] + d[j] + e[j];
    }
}

// unpack short8 (8 bf16) and add into a[0..7]
__device__ __forceinline__ void acc_bf8(float* a, short8 s) {
    u32x4 u = __builtin_bit_cast(u32x4, s);
#pragma unroll
    for (int j = 0; j < 4; ++j) {
        a[2 * j]     += __builtin_bit_cast(float, u[j] << 16);
        a[2 * j + 1] += __builtin_bit_cast(float, u[j] & 0xffff0000u);
    }
}

// -------- weight pre-transform: w[o,i,k] (f32) -> bf16 MFMA B-fragment packed --------
// Wt2[((kb*16 + nf)*64 + l)*8 + j] = bf16(B[kb*32 + (l>>4)*8 + j][nf*16 + (l&15)])
// B[kappa][o] = w[o, i=kappa%256, kpos=kappa/256]
// 384 blocks: amortizes the unavoidably-strided w reads across CUs (round-12 lesson:
// folding this into the 48-block precompute starves 208 CUs and is 14x slower).
template <int S>
__device__ __forceinline__ void transform_body(const float* __restrict__ w,
                                               short* __restrict__ dst, int bid, int tid) {
    int idx = bid * 256 + tid;
    int l  = idx & 63;
    int nf = (idx >> 6) & 15;
    int kb = idx >> 10;
    int o = nf * 16 + (l & 15);
    int kap0 = kb * 32 + ((l >> 4) << 3);
    short8 r;
#pragma unroll
    for (int j = 0; j < 8; ++j) {
        int kap = kap0 + j;
        int kpos = kap >> 8;
        int i = kap & 255;
        r[j] = f2b(w[(o * 256 + i) * S + kpos]);
    }
    *(short8*)(dst + idx * 8) = r;
}

__global__ __launch_bounds__(256) void transform_both(
        const float* __restrict__ w4, const float* __restrict__ w8,
        short* __restrict__ wt4, short* __restrict__ wt8) {
    int bid = blockIdx.x, tid = threadIdx.x;
    if (bid < 128) transform_body<4>(w4, wt4, bid, tid);
    else           transform_body<8>(w8, wt8, bid - 128, tid);
}

// -------- precompute: P[k][R][o] = sum_i T[R][i] * w[o,i,k]  (bf16 out) --------
// Stacked table rows R: [0,17)=val_emb+DEP-ROW (depth folded), [17,81)=pos0,
// [81,145)=pos1, [145,209)=pos2, [209,256)=zero.  bid = k*4 + mt.
template <int S>
__device__ __forceinline__ void precompute_body(
        const float* __restrict__ val_emb, const float* __restrict__ dep_emb,
        const float* __restrict__ pos_emb, const short* __restrict__ wt2,
        short* __restrict__ P, int bid, int tid, short* As) {
    constexpr int LI = (S == 4) ? 3 : 4;
    const int lane = tid & 63;
    const int wid = tid >> 6;
    const int wave_m = wid >> 1;
    const int wave_n = wid & 1;
    const int k  = bid >> 2;
    const int mt = bid & 3;

    f32x4 acc[2][8];
#pragma unroll
    for (int i = 0; i < 2; ++i)
#pragma unroll
        for (int j = 0; j < 8; ++j) acc[i][j] = (f32x4){0.f, 0.f, 0.f, 0.f};

    const int tk = tid >> 5;
    const int f0 = (tid & 31) * 8;
    const float* dep = dep_emb + (LI * 33 + LI + 1) * 256;   // depth row for this layer

#pragma unroll
    for (int m8 = 0; m8 < 8; ++m8) {
        int m = m8 * 8 + tk;
        int R = mt * 64 + m;
        short8 r;
        if (R < 17) {
            const float* src = val_emb + (LI * 17 + R) * 256;
#pragma unroll
            for (int j = 0; j < 8; ++j) r[j] = f2b(src[f0 + j] + dep[f0 + j]);
        } else if (R < 209) {
            int ax = (R < 81) ? 0 : (R < 145 ? 1 : 2);
            int rr = R - (ax == 0 ? 17 : (ax == 1 ? 81 : 145));
            const float* src = pos_emb + ((LI * 3 + ax) * 64 + rr) * 256;
#pragma unroll
            for (int j = 0; j < 8; ++j) r[j] = f2b(src[f0 + j]);
        } else {
            r = (short8){0, 0, 0, 0, 0, 0, 0, 0};
        }
        int byte = (m * 512 + f0 * 2) ^ ((m & 7) << 4);
        *(short8*)((char*)As + byte) = r;
    }
    __syncthreads();

#pragma unroll
    for (int ks = 0; ks < 8; ++ks) {
        short8 af[2];
#pragma unroll
        for (int mf = 0; mf < 2; ++mf) {
            int m = wave_m * 32 + mf * 16 + (lane & 15);
            int byte = (m * 512 + ks * 64 + ((lane >> 4) << 4)) ^ ((m & 7) << 4);
            af[mf] = *(const short8*)((const char*)As + byte);
        }
        int kbg = k * 8 + ks;
#pragma unroll
        for (int nf = 0; nf < 8; ++nf) {
            int nfg = wave_n * 8 + nf;
            short8 bfr = *(const short8*)(wt2 + ((kbg * 16 + nfg) * 64 + lane) * 8);
            acc[0][nf] = __builtin_amdgcn_mfma_f32_16x16x32_bf16(af[0], bfr, acc[0][nf], 0, 0, 0);
            acc[1][nf] = __builtin_amdgcn_mfma_f32_16x16x32_bf16(af[1], bfr, acc[1][nf], 0, 0, 0);
        }
    }

#pragma unroll
    for (int mf = 0; mf < 2; ++mf) {
#pragma unroll
        for (int nf = 0; nf < 8; ++nf) {
            int n = wave_n * 128 + nf * 16 + (lane & 15);
            int r0 = mt * 64 + wave_m * 32 + mf * 16 + ((lane >> 4) << 2);
#pragma unroll
            for (int reg = 0; reg < 4; ++reg)
                P[(k * 256 + r0 + reg) * 256 + n] = f2b(acc[mf][nf][reg]);
        }
    }
}

__global__ __launch_bounds__(256) void precompute_both(
        const float* __restrict__ val_emb, const float* __restrict__ dep_emb,
        const float* __restrict__ pos_emb, const short* __restrict__ wt4,
        const short* __restrict__ wt8, short* __restrict__ P4, short* __restrict__ P8) {
    __shared__ __align__(16) short As[64 * 256];
    if (blockIdx.x < 16)
        precompute_body<4>(val_emb, dep_emb, pos_emb, wt4, P4, blockIdx.x, threadIdx.x, As);
    else
        precompute_body<8>(val_emb, dep_emb, pos_emb, wt8, P8, blockIdx.x - 16, threadIdx.x, As);
}

// -------- gather-sum of bf16 projected rows (1-ahead software pipeline) --------
template <int S>
__device__ __forceinline__ void gather_body(
        const int* __restrict__ value, const int* __restrict__ position,
        const short* __restrict__ P, const float* __restrict__ bias,
        float* __restrict__ out, int bid, int tid, int4* idx_lds) {
    constexpr int L_OUT = (S == 4) ? 1024 : 4096;
    constexpr int OFF_IN = (S == 4) ? 584 : 4680;
    constexpr int OFF_OUT = (S == 4) ? 584 : 1608;

    const int R0 = bid * 8;
    if (tid < 8 * S) {
        int r = tid / S, k = tid - r * S;
        int R = R0 + r;
        int b = R / L_OUT, l = R - b * L_OUT;
        int t = b * S_TOT + OFF_IN + l * S + k;
        int v = value[t];
        const int* pp = position + t * 3;
        idx_lds[r * S + k] = make_int4(v << 8, (17 + pp[0]) << 8,
                                       (81 + pp[1]) << 8, (145 + pp[2]) << 8);
    }
    __syncthreads();

    const int r = tid >> 5;
    const int og = (tid & 31) * 8;
    const int R = R0 + r;
    const int b = R / L_OUT, l = R - b * L_OUT;

    float a[8];
    f32x4 b0 = *(const f32x4*)(bias + og);
    f32x4 b1 = *(const f32x4*)(bias + og + 4);
#pragma unroll
    for (int j = 0; j < 4; ++j) { a[j] = b0[j]; a[4 + j] = b1[j]; }

    const short* Pg = P + og;
    int4 id0 = idx_lds[r * S];
    short8 s0 = *(const short8*)(Pg + id0.x);
    short8 s1 = *(const short8*)(Pg + id0.y);
    short8 s2 = *(const short8*)(Pg + id0.z);
    short8 s3 = *(const short8*)(Pg + id0.w);
#pragma unroll
    for (int k = 0; k < S; ++k) {
        short8 t0 = s0, t1 = s1, t2 = s2, t3 = s3;
        if (k + 1 < S) {
            int4 idn = idx_lds[r * S + k + 1];
            const short* Pn = Pg + ((k + 1) << 16);
            t0 = *(const short8*)(Pn + idn.x);
            t1 = *(const short8*)(Pn + idn.y);
            t2 = *(const short8*)(Pn + idn.z);
            t3 = *(const short8*)(Pn + idn.w);
        }
        acc_bf8(a, s0);
        acc_bf8(a, s1);
        acc_bf8(a, s2);
        acc_bf8(a, s3);
        s0 = t0; s1 = t1; s2 = t2; s3 = t3;
    }

    float* op = out + ((long)b * OUT_ROWS + OFF_OUT + l) * EDIM + og;
    *(f32x4*)op = (f32x4){a[0], a[1], a[2], a[3]};
    *(f32x4*)(op + 4) = (f32x4){a[4], a[5], a[6], a[7]};
}

// -------- layers 0..2: pure embedding, f32 out --------
__device__ __forceinline__ void embed_small_body(
        const int* __restrict__ value, const int* __restrict__ depth,
        const int* __restrict__ position, const float* __restrict__ val_emb,
        const float* __restrict__ dep_emb, const float* __restrict__ pos_emb,
        float* __restrict__ out, int bid, int tid) {
    int idx = bid * 256 + tid;
    int token = idx >> 5;
    int f0 = (idx & 31) * 8;
    int b = token / 584;
    int r = token - b * 584;
    int li = (r < 8) ? 0 : (r < 72 ? 1 : 2);
    int base = b * S_TOT + r;
    int v = value[base];
    int d = depth[base];
    const int* pp = position + base * 3;
    const float* ve = val_emb + ((li * 17 + v) << 8) + f0;
    const float* de = dep_emb + ((li * 33 + d) << 8) + f0;
    const float* q0 = pos_emb + (((li * 3 + 0) * 64 + pp[0]) << 8) + f0;
    const float* q1 = pos_emb + (((li * 3 + 1) * 64 + pp[1]) << 8) + f0;
    const float* q2 = pos_emb + (((li * 3 + 2) * 64 + pp[2]) << 8) + f0;
    float s[8];
    embed8f(ve, de, q0, q1, q2, s);
    float* op = out + ((long)b * OUT_ROWS + r) * EDIM + f0;
    *(f32x4*)op = (f32x4){s[0], s[1], s[2], s[3]};
    *(f32x4*)(op + 4) = (f32x4){s[4], s[5], s[6], s[7]};
}

// -------- mega kernel: gather8 | gather4 | small-embed, one launch --------
__global__ __launch_bounds__(256) void gather_mega(
        const int* __restrict__ value, const int* __restrict__ depth,
        const int* __restrict__ position, const float* __restrict__ val_emb,
        const float* __restrict__ dep_emb, const float* __restrict__ pos_emb,
        const short* __restrict__ P4, const short* __restrict__ P8,
        const float* __restrict__ b4, const float* __restrict__ b8,
        float* __restrict__ out) {
    __shared__ int4 idx_lds[64];
    int bid = blockIdx.x, tid = threadIdx.x;
    if (bid < 4096)
        gather_body<8>(value, position, P8, b8, out, bid, tid, idx_lds);
    else if (bid < 5120)
        gather_body<4>(value, position, P4, b4, out, bid - 4096, tid, idx_lds);
    else
        embed_small_body(value, depth, position, val_emb, dep_emb, pos_emb, out, bid - 5120, tid);
}

// ================= FALLBACK path (round-8 validated) =================
__global__ __launch_bounds__(256) void embed_small_kernel(
        const int* __restrict__ value, const int* __restrict__ depth,
        const int* __restrict__ position, const float* __restrict__ val_emb,
        const float* __restrict__ dep_emb, const float* __restrict__ pos_emb,
        float* __restrict__ out) {
    embed_small_body(value, depth, position, val_emb, dep_emb, pos_emb, out,
                     blockIdx.x, threadIdx.x);
}

template <int S>
__global__ __launch_bounds__(256) void conv_kernel(
        const int* __restrict__ value, const int* __restrict__ depth,
        const int* __restrict__ position, const float* __restrict__ val_emb,
        const float* __restrict__ dep_emb, const float* __restrict__ pos_emb,
        const short* __restrict__ wt2, const float* __restrict__ bias,
        float* __restrict__ out) {
    constexpr int LI = (S == 4) ? 3 : 4;
    constexpr int L_OUT = (S == 4) ? 1024 : 4096;
    constexpr int OFF_IN = (S == 4) ? 584 : 4680;
    constexpr int OFF_OUT = (S == 4) ? 584 : 1608;

    __shared__ __align__(16) short As[64 * 256];

    const int tid = threadIdx.x;
    const int lane = tid & 63;
    const int wid = tid >> 6;
    const int wave_m = wid >> 1;
    const int wave_n = wid & 1;
    const int mg0 = blockIdx.x * 64;
    const int b = mg0 / L_OUT;
    const int l0 = mg0 - b * L_OUT;

    f32x4 acc[2][8];
#pragma unroll
    for (int i = 0; i < 2; ++i)
#pragma unroll
        for (int j = 0; j < 8; ++j) acc[i][j] = (f32x4){0.f, 0.f, 0.f, 0.f};

    const int tk = tid >> 5;
    const int f0 = (tid & 31) * 8;

    for (int cp = 0; cp < S; ++cp) {
        __syncthreads();
#pragma unroll
        for (int m8 = 0; m8 < 8; ++m8) {
            int m = m8 * 8 + tk;
            int t = OFF_IN + (l0 + m) * S + cp;
            int base = b * S_TOT + t;
            int v = value[base];
            int d = depth[base];
            const int* pp = position + base * 3;
            const float* ve = val_emb + ((LI * 17 + v) << 8) + f0;
            const float* de = dep_emb + ((LI * 33 + d) << 8) + f0;
            const float* q0 = pos_emb + (((LI * 3 + 0) * 64 + pp[0]) << 8) + f0;
            const float* q1 = pos_emb + (((LI * 3 + 1) * 64 + pp[1]) << 8) + f0;
            const float* q2 = pos_emb + (((LI * 3 + 2) * 64 + pp[2]) << 8) + f0;
            float s[8];
            embed8f(ve, de, q0, q1, q2, s);
            short8 r;
#pragma unroll
            for (int j = 0; j < 8; ++j) r[j] = f2b(s[j]);
            int byte = (m * 512 + f0 * 2) ^ ((m & 7) << 4);
            *(short8*)((char*)As + byte) = r;
        }
        __syncthreads();
#pragma unroll
        for (int ks = 0; ks < 8; ++ks) {
            short8 af[2];
#pragma unroll
            for (int mf = 0; mf < 2; ++mf) {
                int m = wave_m * 32 + mf * 16 + (lane & 15);
                int byte = (m * 512 + ks * 64 + ((lane >> 4) << 4)) ^ ((m & 7) << 4);
                af[mf] = *(const short8*)((const char*)As + byte);
            }
            int kbg = cp * 8 + ks;
#pragma unroll
            for (int nf = 0; nf < 8; ++nf) {
                int nfg = wave_n * 8 + nf;
                short8 bfr = *(const short8*)(wt2 + ((kbg * 16 + nfg) * 64 + lane) * 8);
                acc[0][nf] = __builtin_amdgcn_mfma_f32_16x16x32_bf16(af[0], bfr, acc[0][nf], 0, 0, 0);
                acc[1][nf] = __builtin_amdgcn_mfma_f32_16x16x32_bf16(af[1], bfr, acc[1][nf], 0, 0, 0);
            }
        }
    }

#pragma unroll
    for (int mf = 0; mf < 2; ++mf) {
#pragma unroll
        for (int nf = 0; nf < 8; ++nf) {
            int n = wave_n * 128 + nf * 16 + (lane & 15);
            float bv = bias[n];
            int r0 = l0 + wave_m * 32 + mf * 16 + ((lane >> 4) << 2);
#pragma unroll
            for (int reg = 0; reg < 4; ++reg)
                out[((long)b * OUT_ROWS + OFF_OUT + r0 + reg) * EDIM + n] =
                    acc[mf][nf][reg] + bv;
        }
    }
}

extern "C" void kernel_launch(void* const* d_in, const int* in_sizes, int n_in,
                              void* d_out, int out_size, void* d_ws, size_t ws_size,
                              hipStream_t stream) {
    const int* value = (const int*)d_in[0];
    const int* depth = (const int*)d_in[1];
    const int* position = (const int*)d_in[2];
    const float* val_emb = (const float*)d_in[3];
    const float* dep_emb = (const float*)d_in[4];
    const float* pos_emb = (const float*)d_in[5];
    const float* w4 = (const float*)d_in[6];
    const float* b4 = (const float*)d_in[7];
    const float* w8 = (const float*)d_in[8];
    const float* b8 = (const float*)d_in[9];
    float* out = (float*)d_out;

    short* wt4 = (short*)d_ws;                          // 512 KB
    short* wt8 = wt4 + 262144;                          // 1 MB
    short* P4  = (short*)((char*)d_ws + 1572864);       // 512 KB (4*256*256 bf16)
    short* P8  = P4 + 262144;                           // 1 MB   (8*256*256 bf16)
    const size_t need = 3145728;

    transform_both<<<dim3(384), dim3(256), 0, stream>>>(w4, w8, wt4, wt8);

    if (ws_size >= need) {
        precompute_both<<<dim3(48), dim3(256), 0, stream>>>(val_emb, dep_emb, pos_emb,
                                                            wt4, wt8, P4, P8);
        gather_mega<<<dim3(5704), dim3(256), 0, stream>>>(value, depth, position,
                                                          val_emb, dep_emb, pos_emb,
                                                          P4, P8, b4, b8, out);
    } else {
        embed_small_kernel<<<dim3(584), dim3(256), 0, stream>>>(value, depth, position,
                                                                val_emb, dep_emb, pos_emb, out);
        conv_kernel<4><<<dim3(128), dim3(256), 0, stream>>>(value, depth, position, val_emb,
                                                            dep_emb, pos_emb, wt4, b4, out);
        conv_kernel<8><<<dim3(512), dim3(256), 0, stream>>>(value, depth, position, val_emb,
                                                            dep_emb, pos_emb, wt8, b8, out);
    }
}

// Round 14
// 61.158 us; speedup vs baseline: 1.5719x; 1.0545x over previous
//
#include <hip/hip_runtime.h>
#include <hip/hip_bf16.h>

// Problem constants
#define S_TOT 37448      // input tokens per sample
#define OUT_ROWS 5704    // output rows per sample
#define EDIM 256
#define BATCH 8

typedef __attribute__((ext_vector_type(8))) short short8;
typedef __attribute__((ext_vector_type(4))) float f32x4;
typedef __attribute__((ext_vector_type(4))) unsigned int u32x4;

__device__ __forceinline__ short f2b(float f) {   // f32 -> bf16 RNE
    unsigned u = __builtin_bit_cast(unsigned, f);
    unsigned r = (u + 0x7fffu + ((u >> 16) & 1u)) >> 16;
    return (short)r;
}
__device__ __forceinline__ float b2f(short s) {
    unsigned u = ((unsigned)(unsigned short)s) << 16;
    return __builtin_bit_cast(float, u);
}

__device__ __forceinline__ void embed8f(const float* ve, const float* de,
                                        const float* q0, const float* q1, const float* q2,
                                        float* s) {
#pragma unroll
    for (int h = 0; h < 2; ++h) {
        f32x4 a = *(const f32x4*)(ve + h * 4);
        f32x4 b = *(const f32x4*)(de + h * 4);
        f32x4 c = *(const f32x4*)(q0 + h * 4);
        f32x4 d = *(const f32x4*)(q1 + h * 4);
        f32x4 e = *(const f32x4*)(q2 + h * 4);
#pragma unroll
        for (int j = 0; j < 4; ++j)
            s[h * 4 + j] = a[j] + b[j] + c[j] + d[j] + e[j];
    }
}

// unpack short8 (8 bf16) and add into a[0..7]
__device__ __forceinline__ void acc_bf8(float* a, short8 s) {
    u32x4 u = __builtin_bit_cast(u32x4, s);
#pragma unroll
    for (int j = 0; j < 4; ++j) {
        a[2 * j]     += __builtin_bit_cast(float, u[j] << 16);
        a[2 * j + 1] += __builtin_bit_cast(float, u[j] & 0xffff0000u);
    }
}

// -------- weight pre-transform: w[o,i,k] (f32) -> bf16 MFMA B-fragment packed --------
// Wt2[((kb*16 + nf)*64 + l)*8 + j] = bf16(B[kb*32 + (l>>4)*8 + j][nf*16 + (l&15)])
// B[kappa][o] = w[o, i=kappa%256, kpos=kappa/256]
// 384 blocks: amortizes the unavoidably-strided w reads across CUs (round-12 lesson:
// folding this into the 48-block precompute starves 208 CUs and is 14x slower).
template <int S>
__device__ __forceinline__ void transform_body(const float* __restrict__ w,
                                               short* __restrict__ dst, int bid, int tid) {
    int idx = bid * 256 + tid;
    int l  = idx & 63;
    int nf = (idx >> 6) & 15;
    int kb = idx >> 10;
    int o = nf * 16 + (l & 15);
    int kap0 = kb * 32 + ((l >> 4) << 3);
    short8 r;
#pragma unroll
    for (int j = 0; j < 8; ++j) {
        int kap = kap0 + j;
        int kpos = kap >> 8;
        int i = kap & 255;
        r[j] = f2b(w[(o * 256 + i) * S + kpos]);
    }
    *(short8*)(dst + idx * 8) = r;
}

__global__ __launch_bounds__(256) void transform_both(
        const float* __restrict__ w4, const float* __restrict__ w8,
        short* __restrict__ wt4, short* __restrict__ wt8) {
    int bid = blockIdx.x, tid = threadIdx.x;
    if (bid < 128) transform_body<4>(w4, wt4, bid, tid);
    else           transform_body<8>(w8, wt8, bid - 128, tid);
}

// -------- precompute: P[k][R][o] = sum_i T[R][i] * w[o,i,k]  (bf16 out) --------
// Stacked table rows R: [0,17)=val_emb+DEP-ROW (depth folded), [17,81)=pos0,
// [81,145)=pos1, [145,209)=pos2, [209,256)=zero.  bid = k*4 + mt.
template <int S>
__device__ __forceinline__ void precompute_body(
        const float* __restrict__ val_emb, const float* __restrict__ dep_emb,
        const float* __restrict__ pos_emb, const short* __restrict__ wt2,
        short* __restrict__ P, int bid, int tid, short* As) {
    constexpr int LI = (S == 4) ? 3 : 4;
    const int lane = tid & 63;
    const int wid = tid >> 6;
    const int wave_m = wid >> 1;
    const int wave_n = wid & 1;
    const int k  = bid >> 2;
    const int mt = bid & 3;

    f32x4 acc[2][8];
#pragma unroll
    for (int i = 0; i < 2; ++i)
#pragma unroll
        for (int j = 0; j < 8; ++j) acc[i][j] = (f32x4){0.f, 0.f, 0.f, 0.f};

    const int tk = tid >> 5;
    const int f0 = (tid & 31) * 8;
    const float* dep = dep_emb + (LI * 33 + LI + 1) * 256;   // depth row for this layer

#pragma unroll
    for (int m8 = 0; m8 < 8; ++m8) {
        int m = m8 * 8 + tk;
        int R = mt * 64 + m;
        short8 r;
        if (R < 17) {
            const float* src = val_emb + (LI * 17 + R) * 256;
#pragma unroll
            for (int j = 0; j < 8; ++j) r[j] = f2b(src[f0 + j] + dep[f0 + j]);
        } else if (R < 209) {
            int ax = (R < 81) ? 0 : (R < 145 ? 1 : 2);
            int rr = R - (ax == 0 ? 17 : (ax == 1 ? 81 : 145));
            const float* src = pos_emb + ((LI * 3 + ax) * 64 + rr) * 256;
#pragma unroll
            for (int j = 0; j < 8; ++j) r[j] = f2b(src[f0 + j]);
        } else {
            r = (short8){0, 0, 0, 0, 0, 0, 0, 0};
        }
        int byte = (m * 512 + f0 * 2) ^ ((m & 7) << 4);
        *(short8*)((char*)As + byte) = r;
    }
    __syncthreads();

#pragma unroll
    for (int ks = 0; ks < 8; ++ks) {
        short8 af[2];
#pragma unroll
        for (int mf = 0; mf < 2; ++mf) {
            int m = wave_m * 32 + mf * 16 + (lane & 15);
            int byte = (m * 512 + ks * 64 + ((lane >> 4) << 4)) ^ ((m & 7) << 4);
            af[mf] = *(const short8*)((const char*)As + byte);
        }
        int kbg = k * 8 + ks;
#pragma unroll
        for (int nf = 0; nf < 8; ++nf) {
            int nfg = wave_n * 8 + nf;
            short8 bfr = *(const short8*)(wt2 + ((kbg * 16 + nfg) * 64 + lane) * 8);
            acc[0][nf] = __builtin_amdgcn_mfma_f32_16x16x32_bf16(af[0], bfr, acc[0][nf], 0, 0, 0);
            acc[1][nf] = __builtin_amdgcn_mfma_f32_16x16x32_bf16(af[1], bfr, acc[1][nf], 0, 0, 0);
        }
    }

#pragma unroll
    for (int mf = 0; mf < 2; ++mf) {
#pragma unroll
        for (int nf = 0; nf < 8; ++nf) {
            int n = wave_n * 128 + nf * 16 + (lane & 15);
            int r0 = mt * 64 + wave_m * 32 + mf * 16 + ((lane >> 4) << 2);
#pragma unroll
            for (int reg = 0; reg < 4; ++reg)
                P[(k * 256 + r0 + reg) * 256 + n] = f2b(acc[mf][nf][reg]);
        }
    }
}

__global__ __launch_bounds__(256) void precompute_both(
        const float* __restrict__ val_emb, const float* __restrict__ dep_emb,
        const float* __restrict__ pos_emb, const short* __restrict__ wt4,
        const short* __restrict__ wt8, short* __restrict__ P4, short* __restrict__ P8) {
    __shared__ __align__(16) short As[64 * 256];
    if (blockIdx.x < 16)
        precompute_body<4>(val_emb, dep_emb, pos_emb, wt4, P4, blockIdx.x, threadIdx.x, As);
    else
        precompute_body<8>(val_emb, dep_emb, pos_emb, wt8, P8, blockIdx.x - 16, threadIdx.x, As);
}

// -------- gather-sum: 32 rows/block, coalesced idx staging, rolling prefetch --------
template <int S>
__device__ __forceinline__ void gather_body32(
        const int* __restrict__ value, const int* __restrict__ position,
        const short* __restrict__ P, const float* __restrict__ bias,
        float* __restrict__ out, int bid, int tid, int4* idx_lds) {
    constexpr int L_OUT = (S == 4) ? 1024 : 4096;
    constexpr int OFF_IN = (S == 4) ? 584 : 4680;
    constexpr int OFF_OUT = (S == 4) ? 584 : 1608;

    const int R0 = bid * 32;                 // 32 rows, never crosses a sample (32 | L_OUT)
    const int b = R0 / L_OUT;
    const int l0 = R0 - b * L_OUT;
    const int tbase = b * S_TOT + OFF_IN + l0 * S;   // 32*S consecutive tokens

    if (tid < 32 * S) {
        int v  = value[tbase + tid];
        int p0 = position[(tbase + tid) * 3 + 0];
        int p1 = position[(tbase + tid) * 3 + 1];
        int p2 = position[(tbase + tid) * 3 + 2];
        idx_lds[tid] = make_int4(v << 8, (17 + p0) << 8,
                                 (81 + p1) << 8, (145 + p2) << 8);
    }
    __syncthreads();

    const int r = tid >> 5;                  // handles rows r, r+8, r+16, r+24
    const int og = (tid & 31) * 8;
    const short* Pg = P + og;
    f32x4 bb0 = *(const f32x4*)(bias + og);
    f32x4 bb1 = *(const f32x4*)(bias + og + 4);

    int4 id = idx_lds[r * S];                // prefetch (rr=0, k=0)
    short8 s0 = *(const short8*)(Pg + id.x);
    short8 s1 = *(const short8*)(Pg + id.y);
    short8 s2 = *(const short8*)(Pg + id.z);
    short8 s3 = *(const short8*)(Pg + id.w);

#pragma unroll
    for (int rr = 0; rr < 4; ++rr) {
        const int row = rr * 8 + r;
        float a[8];
#pragma unroll
        for (int j = 0; j < 4; ++j) { a[j] = bb0[j]; a[4 + j] = bb1[j]; }
#pragma unroll
        for (int k = 0; k < S; ++k) {
            short8 t0 = s0, t1 = s1, t2 = s2, t3 = s3;
            const bool more = !(rr == 3 && k == S - 1);
            if (more) {
                const int nk = (k + 1 < S) ? k + 1 : 0;
                const int nrow = (k + 1 < S) ? row : row + 8;
                int4 idn = idx_lds[nrow * S + nk];
                const short* Pn = Pg + (nk << 16);
                t0 = *(const short8*)(Pn + idn.x);
                t1 = *(const short8*)(Pn + idn.y);
                t2 = *(const short8*)(Pn + idn.z);
                t3 = *(const short8*)(Pn + idn.w);
            }
            acc_bf8(a, s0);
            acc_bf8(a, s1);
            acc_bf8(a, s2);
            acc_bf8(a, s3);
            s0 = t0; s1 = t1; s2 = t2; s3 = t3;
        }
        float* op = out + ((long)b * OUT_ROWS + OFF_OUT + l0 + row) * EDIM + og;
        __builtin_nontemporal_store((f32x4){a[0], a[1], a[2], a[3]}, (f32x4*)op);
        __builtin_nontemporal_store((f32x4){a[4], a[5], a[6], a[7]}, (f32x4*)(op + 4));
    }
}

// -------- layers 0..2: pure embedding, f32 out --------
__device__ __forceinline__ void embed_small_body(
        const int* __restrict__ value, const int* __restrict__ depth,
        const int* __restrict__ position, const float* __restrict__ val_emb,
        const float* __restrict__ dep_emb, const float* __restrict__ pos_emb,
        float* __restrict__ out, int bid, int tid) {
    int idx = bid * 256 + tid;
    int token = idx >> 5;
    int f0 = (idx & 31) * 8;
    int b = token / 584;
    int r = token - b * 584;
    int li = (r < 8) ? 0 : (r < 72 ? 1 : 2);
    int base = b * S_TOT + r;
    int v = value[base];
    int d = depth[base];
    const int* pp = position + base * 3;
    const float* ve = val_emb + ((li * 17 + v) << 8) + f0;
    const float* de = dep_emb + ((li * 33 + d) << 8) + f0;
    const float* q0 = pos_emb + (((li * 3 + 0) * 64 + pp[0]) << 8) + f0;
    const float* q1 = pos_emb + (((li * 3 + 1) * 64 + pp[1]) << 8) + f0;
    const float* q2 = pos_emb + (((li * 3 + 2) * 64 + pp[2]) << 8) + f0;
    float s[8];
    embed8f(ve, de, q0, q1, q2, s);
    float* op = out + ((long)b * OUT_ROWS + r) * EDIM + f0;
    *(f32x4*)op = (f32x4){s[0], s[1], s[2], s[3]};
    *(f32x4*)(op + 4) = (f32x4){s[4], s[5], s[6], s[7]};
}

// -------- mega kernel: gather8 | gather4 | small-embed, one launch --------
// grid: [0,1024) gather8 (32 rows each), [1024,1280) gather4, [1280,1864) embed
__global__ __launch_bounds__(256) void gather_mega(
        const int* __restrict__ value, const int* __restrict__ depth,
        const int* __restrict__ position, const float* __restrict__ val_emb,
        const float* __restrict__ dep_emb, const float* __restrict__ pos_emb,
        const short* __restrict__ P4, const short* __restrict__ P8,
        const float* __restrict__ b4, const float* __restrict__ b8,
        float* __restrict__ out) {
    __shared__ int4 idx_lds[256];
    int bid = blockIdx.x, tid = threadIdx.x;
    if (bid < 1024)
        gather_body32<8>(value, position, P8, b8, out, bid, tid, idx_lds);
    else if (bid < 1280)
        gather_body32<4>(value, position, P4, b4, out, bid - 1024, tid, idx_lds);
    else
        embed_small_body(value, depth, position, val_emb, dep_emb, pos_emb, out, bid - 1280, tid);
}

// ================= FALLBACK path (round-8 validated) =================
__global__ __launch_bounds__(256) void embed_small_kernel(
        const int* __restrict__ value, const int* __restrict__ depth,
        const int* __restrict__ position, const float* __restrict__ val_emb,
        const float* __restrict__ dep_emb, const float* __restrict__ pos_emb,
        float* __restrict__ out) {
    embed_small_body(value, depth, position, val_emb, dep_emb, pos_emb, out,
                     blockIdx.x, threadIdx.x);
}

template <int S>
__global__ __launch_bounds__(256) void conv_kernel(
        const int* __restrict__ value, const int* __restrict__ depth,
        const int* __restrict__ position, const float* __restrict__ val_emb,
        const float* __restrict__ dep_emb, const float* __restrict__ pos_emb,
        const short* __restrict__ wt2, const float* __restrict__ bias,
        float* __restrict__ out) {
    constexpr int LI = (S == 4) ? 3 : 4;
    constexpr int L_OUT = (S == 4) ? 1024 : 4096;
    constexpr int OFF_IN = (S == 4) ? 584 : 4680;
    constexpr int OFF_OUT = (S == 4) ? 584 : 1608;

    __shared__ __align__(16) short As[64 * 256];

    const int tid = threadIdx.x;
    const int lane = tid & 63;
    const int wid = tid >> 6;
    const int wave_m = wid >> 1;
    const int wave_n = wid & 1;
    const int mg0 = blockIdx.x * 64;
    const int b = mg0 / L_OUT;
    const int l0 = mg0 - b * L_OUT;

    f32x4 acc[2][8];
#pragma unroll
    for (int i = 0; i < 2; ++i)
#pragma unroll
        for (int j = 0; j < 8; ++j) acc[i][j] = (f32x4){0.f, 0.f, 0.f, 0.f};

    const int tk = tid >> 5;
    const int f0 = (tid & 31) * 8;

    for (int cp = 0; cp < S; ++cp) {
        __syncthreads();
#pragma unroll
        for (int m8 = 0; m8 < 8; ++m8) {
            int m = m8 * 8 + tk;
            int t = OFF_IN + (l0 + m) * S + cp;
            int base = b * S_TOT + t;
            int v = value[base];
            int d = depth[base];
            const int* pp = position + base * 3;
            const float* ve = val_emb + ((LI * 17 + v) << 8) + f0;
            const float* de = dep_emb + ((LI * 33 + d) << 8) + f0;
            const float* q0 = pos_emb + (((LI * 3 + 0) * 64 + pp[0]) << 8) + f0;
            const float* q1 = pos_emb + (((LI * 3 + 1) * 64 + pp[1]) << 8) + f0;
            const float* q2 = pos_emb + (((LI * 3 + 2) * 64 + pp[2]) << 8) + f0;
            float s[8];
            embed8f(ve, de, q0, q1, q2, s);
            short8 r;
#pragma unroll
            for (int j = 0; j < 8; ++j) r[j] = f2b(s[j]);
            int byte = (m * 512 + f0 * 2) ^ ((m & 7) << 4);
            *(short8*)((char*)As + byte) = r;
        }
        __syncthreads();
#pragma unroll
        for (int ks = 0; ks < 8; ++ks) {
            short8 af[2];
#pragma unroll
            for (int mf = 0; mf < 2; ++mf) {
                int m = wave_m * 32 + mf * 16 + (lane & 15);
                int byte = (m * 512 + ks * 64 + ((lane >> 4) << 4)) ^ ((m & 7) << 4);
                af[mf] = *(const short8*)((const char*)As + byte);
            }
            int kbg = cp * 8 + ks;
#pragma unroll
            for (int nf = 0; nf < 8; ++nf) {
                int nfg = wave_n * 8 + nf;
                short8 bfr = *(const short8*)(wt2 + ((kbg * 16 + nfg) * 64 + lane) * 8);
                acc[0][nf] = __builtin_amdgcn_mfma_f32_16x16x32_bf16(af[0], bfr, acc[0][nf], 0, 0, 0);
                acc[1][nf] = __builtin_amdgcn_mfma_f32_16x16x32_bf16(af[1], bfr, acc[1][nf], 0, 0, 0);
            }
        }
    }

#pragma unroll
    for (int mf = 0; mf < 2; ++mf) {
#pragma unroll
        for (int nf = 0; nf < 8; ++nf) {
            int n = wave_n * 128 + nf * 16 + (lane & 15);
            float bv = bias[n];
            int r0 = l0 + wave_m * 32 + mf * 16 + ((lane >> 4) << 2);
#pragma unroll
            for (int reg = 0; reg < 4; ++reg)
                out[((long)b * OUT_ROWS + OFF_OUT + r0 + reg) * EDIM + n] =
                    acc[mf][nf][reg] + bv;
        }
    }
}

extern "C" void kernel_launch(void* const* d_in, const int* in_sizes, int n_in,
                              void* d_out, int out_size, void* d_ws, size_t ws_size,
                              hipStream_t stream) {
    const int* value = (const int*)d_in[0];
    const int* depth = (const int*)d_in[1];
    const int* position = (const int*)d_in[2];
    const float* val_emb = (const float*)d_in[3];
    const float* dep_emb = (const float*)d_in[4];
    const float* pos_emb = (const float*)d_in[5];
    const float* w4 = (const float*)d_in[6];
    const float* b4 = (const float*)d_in[7];
    const float* w8 = (const float*)d_in[8];
    const float* b8 = (const float*)d_in[9];
    float* out = (float*)d_out;

    short* wt4 = (short*)d_ws;                          // 512 KB
    short* wt8 = wt4 + 262144;                          // 1 MB
    short* P4  = (short*)((char*)d_ws + 1572864);       // 512 KB (4*256*256 bf16)
    short* P8  = P4 + 262144;                           // 1 MB   (8*256*256 bf16)
    const size_t need = 3145728;

    transform_both<<<dim3(384), dim3(256), 0, stream>>>(w4, w8, wt4, wt8);

    if (ws_size >= need) {
        precompute_both<<<dim3(48), dim3(256), 0, stream>>>(val_emb, dep_emb, pos_emb,
                                                            wt4, wt8, P4, P8);
        gather_mega<<<dim3(1864), dim3(256), 0, stream>>>(value, depth, position,
                                                          val_emb, dep_emb, pos_emb,
                                                          P4, P8, b4, b8, out);
    } else {
        embed_small_kernel<<<dim3(584), dim3(256), 0, stream>>>(value, depth, position,
                                                                val_emb, dep_emb, pos_emb, out);
        conv_kernel<4><<<dim3(128), dim3(256), 0, stream>>>(value, depth, position, val_emb,
                                                            dep_emb, pos_emb, wt4, b4, out);
        conv_kernel<8><<<dim3(512), dim3(256), 0, stream>>>(value, depth, position, val_emb,
                                                            dep_emb, pos_emb, wt8, b8, out);
    }
}